// Round 2
// baseline (1763.320 us; speedup 1.0000x reference)
//
#include <hip/hip_runtime.h>
#include <cstdint>

typedef __bf16 bf16;
typedef __bf16 bf16x8 __attribute__((ext_vector_type(8)));
typedef __bf16 bf16x4 __attribute__((ext_vector_type(4)));
typedef float  f32x4  __attribute__((ext_vector_type(4)));

#define BQ     2
#define LQ     2048
#define DMODEL 2048
#define INTER  4096
#define NH     64
#define HD     64
#define NS     128
#define CS     256
#define NC     8
#define CONVD  4352
#define PROJD  8512
#define PROJP  8576   /* padded to 128-multiple */
#define MTOT   4096   /* B*L */
#define EPSF   1e-5f

// ---------------------------------------------------------------- utilities
__device__ __forceinline__ void async_ld16(const bf16* g, bf16* l) {
  __builtin_amdgcn_global_load_lds(
      (__attribute__((address_space(1))) void*)(uintptr_t)g,
      (__attribute__((address_space(3))) void*)l, 16, 0, 0);
}

__device__ __forceinline__ float siluf(float x) { return x / (1.f + expf(-x)); }

// ---------------------------------------------------------------- casts
__global__ void cast4_k(const float* __restrict__ in, bf16* __restrict__ out, long n4) {
  long i = (long)blockIdx.x * 256 + threadIdx.x;
  if (i >= n4) return;
  float4 v = ((const float4*)in)[i];
  bf16x4 o; o[0] = (bf16)v.x; o[1] = (bf16)v.y; o[2] = (bf16)v.z; o[3] = (bf16)v.w;
  ((bf16x4*)out)[i] = o;
}

__global__ void cast_pad_win_k(const float* __restrict__ W, bf16* __restrict__ out) {
  long i = (long)blockIdx.x * 256 + threadIdx.x;       // over PROJP * (DMODEL/4)
  long tot = (long)PROJP * (DMODEL / 4);
  if (i >= tot) return;
  long row = i / (DMODEL / 4);
  long k4  = i % (DMODEL / 4);
  bf16x4 o;
  if (row < PROJD) {
    float4 v = ((const float4*)W)[row * (DMODEL / 4) + k4];
    o[0] = (bf16)v.x; o[1] = (bf16)v.y; o[2] = (bf16)v.z; o[3] = (bf16)v.w;
  } else {
    o[0] = o[1] = o[2] = o[3] = (bf16)0.f;
  }
  ((bf16x4*)out)[i] = o;
}

// ---------------------------------------------------------------- GEMM  C = A(MxK) * W(NxK)^T
#define BM 128
#define BN 128
#define BK 32

__global__ __launch_bounds__(256) void gemm_bt(
    const bf16* __restrict__ A, const bf16* __restrict__ W,
    bf16* __restrict__ Cb, float* __restrict__ Cf,
    int M, int Nn, int K, int outf32)
{
  __shared__ bf16 As[BM * BK];
  __shared__ bf16 Bs[BN * BK];
  const int tid  = threadIdx.x;
  const int wave = tid >> 6;
  const int lane = tid & 63;
  const long tm = (long)blockIdx.y * BM;
  const long tn = (long)blockIdx.x * BN;
  const int wm = (wave >> 1) * 64;
  const int wn = (wave & 1) * 64;
  const int quad = lane >> 4;
  const int r16  = lane & 15;

  f32x4 acc[4][4] = {};

  for (long k0 = 0; k0 < K; k0 += BK) {
    __syncthreads();
    #pragma unroll
    for (int p = 0; p < 2; ++p) {
      int row = p * 64 + (tid >> 2);
      int kc  = (tid & 3) * 8;
      async_ld16(A + (tm + row) * K + k0 + kc, &As[(p * 256 + wave * 64) * 8]);
      async_ld16(W + (tn + row) * K + k0 + kc, &Bs[(p * 256 + wave * 64) * 8]);
    }
    __syncthreads();
    bf16x8 af[4], bfr[4];
    #pragma unroll
    for (int i = 0; i < 4; ++i)
      af[i] = *(const bf16x8*)&As[(wm + i * 16 + r16) * BK + quad * 8];
    #pragma unroll
    for (int j = 0; j < 4; ++j)
      bfr[j] = *(const bf16x8*)&Bs[(wn + j * 16 + r16) * BK + quad * 8];
    #pragma unroll
    for (int i = 0; i < 4; ++i)
      #pragma unroll
      for (int j = 0; j < 4; ++j)
        acc[i][j] = __builtin_amdgcn_mfma_f32_16x16x32_bf16(af[i], bfr[j], acc[i][j], 0, 0, 0);
  }

  #pragma unroll
  for (int i = 0; i < 4; ++i)
    #pragma unroll
    for (int j = 0; j < 4; ++j) {
      long r0 = tm + wm + i * 16 + quad * 4;
      long cc = tn + wn + j * 16 + r16;
      #pragma unroll
      for (int reg = 0; reg < 4; ++reg) {
        long idx = (r0 + reg) * (long)Nn + cc;
        if (outf32) Cf[idx] = acc[i][j][reg];
        else        Cb[idx] = (bf16)acc[i][j][reg];
      }
    }
}

// ---------------------------------------------------------------- depthwise causal conv + silu + split
__global__ void conv_silu_k(const bf16* __restrict__ proj,
                            const float* __restrict__ conv_w,
                            const float* __restrict__ conv_b,
                            bf16* __restrict__ xconv,
                            float* __restrict__ Bm, float* __restrict__ Cm)
{
  int ch = blockIdx.x * 256 + threadIdx.x;
  if (ch >= CONVD) return;
  long bl = blockIdx.y;
  int l = (int)(bl & (LQ - 1));
  float acc = conv_b[ch];
  #pragma unroll
  for (int t = 0; t < 4; ++t) {
    int ls = l - 3 + t;
    if (ls >= 0)
      acc += (float)proj[(bl - 3 + t) * PROJP + INTER + ch] * conv_w[ch * 4 + t];
  }
  float y = siluf(acc);
  if (ch < INTER)            xconv[bl * INTER + ch] = (bf16)y;
  else if (ch < INTER + NS)  Bm[bl * NS + (ch - INTER)] = y;
  else                       Cm[bl * NS + (ch - INTER - NS)] = y;
}

// ---------------------------------------------------------------- dt softplus + per-chunk cumsum of dA
__global__ __launch_bounds__(CS) void dt_prep_k(
    const bf16* __restrict__ proj, const float* __restrict__ dt_bias,
    const float* __restrict__ A_log,
    float* __restrict__ dtv, float* __restrict__ acum, float* __restrict__ cdec)
{
  int bx = blockIdx.x;          // (b*NH + h)*NC + ci
  int ci = bx & 7;
  int bh = bx >> 3;
  int h  = bh & 63;
  int b  = bh >> 6;
  int i  = threadIdx.x;
  long pos = (long)b * LQ + ci * CS + i;
  float draw = (float)proj[pos * PROJP + INTER + CONVD + h] + dt_bias[h];
  float dv = draw > 20.f ? draw : log1pf(expf(draw));
  float Ah = -expf(A_log[h]);
  __shared__ float s[CS];
  s[i] = dv * Ah;
  __syncthreads();
  for (int off = 1; off < CS; off <<= 1) {
    float t = (i >= off) ? s[i - off] : 0.f;
    __syncthreads();
    s[i] += t;
    __syncthreads();
  }
  long base = (long)bx * CS;
  dtv[base + i]  = dv;
  acum[base + i] = s[i];
  if (i == 0) cdec[bx] = expf(s[CS - 1]);
}

// ---------------------------------------------------------------- G^T[j][i] = C_i . B_j  (head-independent, G=1)
__global__ __launch_bounds__(256) void gmat_k(
    const float* __restrict__ Bm, const float* __restrict__ Cm, float* __restrict__ Gt)
{
  int bc = blockIdx.x;          // b*NC + ci
  int it = blockIdx.y;          // 0..3 row tile
  int t  = threadIdx.x;
  long bl0 = (long)(bc >> 3) * LQ + (bc & 7) * CS;
  __shared__ float Cs[64][129];
  for (int r = 0; r < 32; ++r) {
    int idx = t + r * 256;
    int il = idx >> 7, n = idx & 127;
    Cs[il][n] = Cm[(bl0 + it * 64 + il) * NS + n];
  }
  __syncthreads();
  int il = t & 63, jg = t >> 6;
  for (int jj = 0; jj < 64; ++jj) {
    int j = jg * 64 + jj;
    const float* brow = &Bm[(bl0 + j) * NS];
    float dot = 0.f;
    #pragma unroll
    for (int n = 0; n < NS; ++n) dot += Cs[il][n] * brow[n];
    Gt[((long)bc * CS + j) * CS + it * 64 + il] = dot;
  }
}

// ---------------------------------------------------------------- chunk states (HD x NS per b,c,h) -> bf16
__global__ __launch_bounds__(256) void states_k(
    const bf16* __restrict__ xconv, const float* __restrict__ Bm,
    const float* __restrict__ dtv, const float* __restrict__ acum,
    bf16* __restrict__ states)
{
  int bx = blockIdx.x;          // bc*NH + h
  int h = bx & 63, bc = bx >> 6;
  int b = bc >> 3, ci = bc & 7;
  long bl0 = (long)b * LQ + ci * CS;
  long abase = ((long)(b * NH + h) * NC + ci) * CS;
  int t = threadIdx.x;
  __shared__ float ac_s[CS];
  __shared__ float ws_s[CS];
  __shared__ float xw[64][64];
  __shared__ float Bl[64][NS];
  ac_s[t] = acum[abase + t];
  __syncthreads();
  float alast = ac_s[CS - 1];
  ws_s[t] = expf(alast - ac_s[t]) * dtv[abase + t];
  int p = t & 63, nb = t >> 6;
  float accv[32] = {};
  for (int jt = 0; jt < 4; ++jt) {
    __syncthreads();
    for (int r = 0; r < 16; ++r) {
      int jj = (t >> 6) + r * 4;
      xw[jj][p] = (float)xconv[(bl0 + jt * 64 + jj) * INTER + h * HD + p] * ws_s[jt * 64 + jj];
    }
    for (int r = 0; r < 32; ++r) {
      int idx = t + r * 256;
      int jj = idx >> 7, n = idx & 127;
      Bl[jj][n] = Bm[(bl0 + jt * 64 + jj) * NS + n];
    }
    __syncthreads();
    for (int jj = 0; jj < 64; ++jj) {
      float xv = xw[jj][p];
      #pragma unroll
      for (int n0 = 0; n0 < 32; ++n0)
        accv[n0] += xv * Bl[jj][nb * 32 + n0];
    }
  }
  long sb = ((long)bx * HD + p) * NS + nb * 32;
  #pragma unroll
  for (int n0 = 0; n0 < 32; ++n0) states[sb + n0] = (bf16)accv[n0];
}

// ---------------------------------------------------------------- inter-chunk scan, IN PLACE (st -> prev)
__global__ void scan_k(bf16* __restrict__ st, const float* __restrict__ cdec)
{
  long t = (long)blockIdx.x * 256 + threadIdx.x;  // (b,h,p,n)
  int n = (int)(t & 127);
  int p = (int)((t >> 7) & 63);
  int h = (int)((t >> 13) & 63);
  int b = (int)(t >> 19);
  float carry = 0.f;
  for (int ci = 0; ci < NC; ++ci) {
    long idx = (((long)(b * NC + ci) * NH + h) * HD + p) * NS + n;
    float v = (float)st[idx];
    st[idx] = (bf16)carry;
    carry = cdec[(b * NH + h) * NC + ci] * carry + v;
  }
}

// ---------------------------------------------------------------- fused Ydiag + Yoff + D*x -> Y (bf16, aliases xconv)
__global__ __launch_bounds__(256) void ymix_k(
    const bf16* __restrict__ xconv, const float* __restrict__ Gt,
    const bf16* __restrict__ prev, const float* __restrict__ Cm,
    const float* __restrict__ dtv, const float* __restrict__ acum,
    const float* __restrict__ Dp, bf16* __restrict__ Y)
{
  int bx = blockIdx.x;          // bc*NH + h
  int h = bx & 63, bc = bx >> 6;
  int b = bc >> 3, ci = bc & 7;
  long bl0 = (long)b * LQ + ci * CS;
  long abase = ((long)(b * NH + h) * NC + ci) * CS;
  int t = threadIdx.x;

  __shared__ float ac_s[CS], dt_s[CS], ea_s[CS];
  __shared__ __align__(16) char sbuf[44032];
  float (*xs)[32] = (float(*)[32])sbuf;              // 32768 B, ydiag phase
  float (*pt)[36] = (float(*)[36])sbuf;              //  9216 B, yoff phase
  bf16  (*Cl)[68] = (bf16 (*)[68])(sbuf + 9216);     // 34816 B, yoff phase

  ac_s[t] = acum[abase + t];
  dt_s[t] = dtv[abase + t];
  ea_s[t] = expf(ac_s[t]);
  int i1 = t, i2 = 255 - t;
  const float* g0 = &Gt[(long)bc * CS * CS];
  float Dh = Dp[h];
  __syncthreads();
  float a1 = ac_s[i1], a2 = ac_s[i2];
  float e1 = ea_s[i1], e2 = ea_s[i2];

  for (int ph = 0; ph < 2; ++ph) {
    if (ph) __syncthreads();               // protect sbuf (Cl) before reuse as xs
    for (int r = 0; r < 32; ++r) {
      int idx = t + r * 256;
      int p = idx & 31, j = idx >> 5;
      xs[j][p] = (float)xconv[(bl0 + j) * INTER + h * HD + ph * 32 + p];
    }
    __syncthreads();
    float acc1[32], acc2[32];
    #pragma unroll
    for (int p = 0; p < 32; ++p) { acc1[p] = Dh * xs[i1][p]; acc2[p] = Dh * xs[i2][p]; }
    for (int j = 0; j < CS; ++j) {
      float aj = ac_s[j], dj = dt_s[j];
      if (j <= i1) {
        float s = g0[(long)j * CS + i1] * expf(a1 - aj) * dj;
        #pragma unroll
        for (int p = 0; p < 32; ++p) acc1[p] += s * xs[j][p];
      }
      if (j <= i2) {
        float s = g0[(long)j * CS + i2] * expf(a2 - aj) * dj;
        #pragma unroll
        for (int p = 0; p < 32; ++p) acc2[p] += s * xs[j][p];
      }
    }
    __syncthreads();                       // done reading xs; sbuf becomes pt/Cl
    for (int nt = 0; nt < 2; ++nt) {
      if (nt) __syncthreads();
      for (int r = 0; r < 8; ++r) {
        int idx = t + r * 256;             // 2048 = 64n * 32p
        int n = idx & 63, p = idx >> 6;
        pt[n][p] = (float)prev[((long)bx * HD + ph * 32 + p) * NS + nt * 64 + n];
      }
      for (int r = 0; r < 64; ++r) {
        int idx = t + r * 256;
        int n = idx & 63, i = idx >> 6;
        Cl[i][n] = (bf16)Cm[(bl0 + i) * NS + nt * 64 + n];
      }
      __syncthreads();
      for (int n = 0; n < 64; ++n) {
        float c1 = e1 * (float)Cl[i1][n];
        float c2 = e2 * (float)Cl[i2][n];
        #pragma unroll
        for (int p = 0; p < 32; ++p) {
          float pv = pt[n][p];
          acc1[p] += c1 * pv;
          acc2[p] += c2 * pv;
        }
      }
    }
    long yb1 = (bl0 + i1) * INTER + h * HD + ph * 32;
    long yb2 = (bl0 + i2) * INTER + h * HD + ph * 32;
    #pragma unroll
    for (int p = 0; p < 32; ++p) Y[yb1 + p] = (bf16)acc1[p];
    #pragma unroll
    for (int p = 0; p < 32; ++p) Y[yb2 + p] = (bf16)acc2[p];
  }
}

// ---------------------------------------------------------------- gate*silu + RMS norm, IN PLACE (Y -> yn)
__global__ __launch_bounds__(256) void norm_k(
    bf16* __restrict__ Y, const bf16* __restrict__ proj,
    const float* __restrict__ norm_w)
{
  long bl = blockIdx.x;
  int t = threadIdx.x;
  __shared__ float yb[INTER];
  __shared__ float red[256];
  float ss = 0.f;
  for (int r = 0; r < 16; ++r) {
    int ch = t + r * 256;
    float g = (float)proj[bl * PROJP + ch];
    float yv = (float)Y[bl * INTER + ch] * siluf(g);
    yb[ch] = yv;
    ss += yv * yv;
  }
  red[t] = ss;
  __syncthreads();
  for (int s = 128; s > 0; s >>= 1) {
    if (t < s) red[t] += red[t + s];
    __syncthreads();
  }
  float scale = rsqrtf(red[0] / (float)INTER + EPSF);
  for (int r = 0; r < 16; ++r) {
    int ch = t + r * 256;
    Y[bl * INTER + ch] = (bf16)(yb[ch] * scale * norm_w[ch]);
  }
}

// ---------------------------------------------------------------- launch
extern "C" void kernel_launch(void* const* d_in, const int* in_sizes, int n_in,
                              void* d_out, int out_size, void* d_ws, size_t ws_size,
                              hipStream_t stream)
{
  (void)in_sizes; (void)n_in; (void)out_size; (void)ws_size;
  const float* hidden  = (const float*)d_in[0];
  const float* W_in    = (const float*)d_in[1];
  const float* conv_w  = (const float*)d_in[2];
  const float* conv_b  = (const float*)d_in[3];
  const float* dt_bias = (const float*)d_in[4];
  const float* A_log   = (const float*)d_in[5];
  const float* Dp      = (const float*)d_in[6];
  const float* norm_w  = (const float*)d_in[7];
  const float* W_out   = (const float*)d_in[8];
  float* out = (float*)d_out;

  // ---- workspace layout with lifetime-based aliasing (peak 131,076,096 B ≈ 125 MiB)
  char* ws    = (char*)d_ws;
  bf16* projb = (bf16*)(ws);                         // 70,254,592  [gemm1 .. norm]
  char* base2 = ws + 70254592;
  bf16*  hb    = (bf16*)(base2);                     // 16,777,216  [stage1 only]
  bf16*  winb  = (bf16*)(base2 + 16777216);          // 35,127,296  [stage1 only]
  bf16*  xconv = (bf16*)(base2);                     // 33,554,432  [conv .. ymix] = Y = yn
  bf16*  st    = (bf16*)(base2 + 33554432);          // 16,777,216  [states .. ymix] = woutb later
  float* Gt    = (float*)(base2 + 50331648);         //  4,194,304
  float* Bm    = (float*)(base2 + 54525952);         //  2,097,152
  float* Cm    = (float*)(base2 + 56623104);         //  2,097,152
  float* dtv   = (float*)(base2 + 58720256);         //  1,048,576
  float* acum  = (float*)(base2 + 59768832);         //  1,048,576
  float* cdec  = (float*)(base2 + 60817408);         //      4,096
  bf16*  Yb    = xconv;                              // alias (disjoint per-block tiles)
  bf16*  yn    = xconv;                              // norm is in-place
  bf16*  woutb = (bf16*)(base2 + 33554432);          // alias st (dead after ymix)

  // stage 1: casts + in-projection GEMM
  cast4_k<<<dim3((unsigned)((MTOT * (long)DMODEL / 4 + 255) / 256)), 256, 0, stream>>>(
      hidden, hb, (long)MTOT * DMODEL / 4);
  cast_pad_win_k<<<dim3((unsigned)(((long)PROJP * (DMODEL / 4) + 255) / 256)), 256, 0, stream>>>(
      W_in, winb);
  gemm_bt<<<dim3(PROJP / BN, MTOT / BM), 256, 0, stream>>>(
      hb, winb, projb, nullptr, MTOT, PROJP, DMODEL, 0);

  // stage 2: conv + SSD
  conv_silu_k<<<dim3(CONVD / 256, MTOT), 256, 0, stream>>>(
      projb, conv_w, conv_b, xconv, Bm, Cm);
  dt_prep_k<<<dim3(BQ * NH * NC), CS, 0, stream>>>(
      projb, dt_bias, A_log, dtv, acum, cdec);
  gmat_k<<<dim3(BQ * NC, 4), 256, 0, stream>>>(Bm, Cm, Gt);
  states_k<<<dim3(BQ * NC * NH), 256, 0, stream>>>(xconv, Bm, dtv, acum, st);
  scan_k<<<dim3(BQ * NH * HD * NS / 256), 256, 0, stream>>>(st, cdec);
  ymix_k<<<dim3(BQ * NC * NH), 256, 0, stream>>>(
      xconv, Gt, st, Cm, dtv, acum, Dp, Yb);

  // stage 3: norm + out-projection GEMM
  cast4_k<<<dim3((unsigned)((DMODEL * (long)INTER / 4 + 255) / 256)), 256, 0, stream>>>(
      W_out, woutb, (long)DMODEL * INTER / 4);
  norm_k<<<dim3(MTOT), 256, 0, stream>>>(Yb, projb, norm_w);
  gemm_bt<<<dim3(DMODEL / BN, MTOT / BM), 256, 0, stream>>>(
      yn, woutb, nullptr, out, MTOT, DMODEL, INTER, 1);
}

// Round 3
// 802.412 us; speedup vs baseline: 2.1975x; 2.1975x over previous
//
#include <hip/hip_runtime.h>
#include <cstdint>

typedef __bf16 bf16;
typedef __bf16 bf16x8 __attribute__((ext_vector_type(8)));
typedef __bf16 bf16x4 __attribute__((ext_vector_type(4)));
typedef float  f32x4  __attribute__((ext_vector_type(4)));

#define BQ     2
#define LQ     2048
#define DMODEL 2048
#define INTER  4096
#define NH     64
#define HD     64
#define NS     128
#define CS     256
#define NC     8
#define CONVD  4352
#define PROJD  8512
#define PROJP  8576   /* padded to 128-multiple */
#define MTOT   4096   /* B*L */
#define EPSF   1e-5f
#define LOG2E  1.44269504088896f

// ---------------------------------------------------------------- utilities
__device__ __forceinline__ void async_ld16(const bf16* g, bf16* l) {
  __builtin_amdgcn_global_load_lds(
      (__attribute__((address_space(1))) void*)(uintptr_t)g,
      (__attribute__((address_space(3))) void*)l, 16, 0, 0);
}

__device__ __forceinline__ float siluf(float x) { return x / (1.f + expf(-x)); }

// ---------------------------------------------------------------- casts
__global__ void cast4_k(const float* __restrict__ in, bf16* __restrict__ out, long n4) {
  long i = (long)blockIdx.x * 256 + threadIdx.x;
  if (i >= n4) return;
  float4 v = ((const float4*)in)[i];
  bf16x4 o; o[0] = (bf16)v.x; o[1] = (bf16)v.y; o[2] = (bf16)v.z; o[3] = (bf16)v.w;
  ((bf16x4*)out)[i] = o;
}

__global__ void cast_pad_win_k(const float* __restrict__ W, bf16* __restrict__ out) {
  long i = (long)blockIdx.x * 256 + threadIdx.x;       // over PROJP * (DMODEL/4)
  long tot = (long)PROJP * (DMODEL / 4);
  if (i >= tot) return;
  long row = i / (DMODEL / 4);
  long k4  = i % (DMODEL / 4);
  bf16x4 o;
  if (row < PROJD) {
    float4 v = ((const float4*)W)[row * (DMODEL / 4) + k4];
    o[0] = (bf16)v.x; o[1] = (bf16)v.y; o[2] = (bf16)v.z; o[3] = (bf16)v.w;
  } else {
    o[0] = o[1] = o[2] = o[3] = (bf16)0.f;
  }
  ((bf16x4*)out)[i] = o;
}

// ---------------------------------------------------------------- GEMM  C = A(MxK) * W(NxK)^T
#define BM 128
#define BN 128
#define BK 32

__global__ __launch_bounds__(256) void gemm_bt(
    const bf16* __restrict__ A, const bf16* __restrict__ W,
    bf16* __restrict__ Cb, float* __restrict__ Cf,
    int M, int Nn, int K, int outf32)
{
  __shared__ bf16 As[BM * BK];
  __shared__ bf16 Bs[BN * BK];
  const int tid  = threadIdx.x;
  const int wave = tid >> 6;
  const int lane = tid & 63;
  const long tm = (long)blockIdx.y * BM;
  const long tn = (long)blockIdx.x * BN;
  const int wm = (wave >> 1) * 64;
  const int wn = (wave & 1) * 64;
  const int quad = lane >> 4;
  const int r16  = lane & 15;

  f32x4 acc[4][4] = {};

  for (long k0 = 0; k0 < K; k0 += BK) {
    __syncthreads();
    #pragma unroll
    for (int p = 0; p < 2; ++p) {
      int row = p * 64 + (tid >> 2);
      int kc  = (tid & 3) * 8;
      async_ld16(A + (tm + row) * K + k0 + kc, &As[(p * 256 + wave * 64) * 8]);
      async_ld16(W + (tn + row) * K + k0 + kc, &Bs[(p * 256 + wave * 64) * 8]);
    }
    __syncthreads();
    bf16x8 af[4], bfr[4];
    #pragma unroll
    for (int i = 0; i < 4; ++i)
      af[i] = *(const bf16x8*)&As[(wm + i * 16 + r16) * BK + quad * 8];
    #pragma unroll
    for (int j = 0; j < 4; ++j)
      bfr[j] = *(const bf16x8*)&Bs[(wn + j * 16 + r16) * BK + quad * 8];
    #pragma unroll
    for (int i = 0; i < 4; ++i)
      #pragma unroll
      for (int j = 0; j < 4; ++j)
        acc[i][j] = __builtin_amdgcn_mfma_f32_16x16x32_bf16(af[i], bfr[j], acc[i][j], 0, 0, 0);
  }

  #pragma unroll
  for (int i = 0; i < 4; ++i)
    #pragma unroll
    for (int j = 0; j < 4; ++j) {
      long r0 = tm + wm + i * 16 + quad * 4;
      long cc = tn + wn + j * 16 + r16;
      #pragma unroll
      for (int reg = 0; reg < 4; ++reg) {
        long idx = (r0 + reg) * (long)Nn + cc;
        if (outf32) Cf[idx] = acc[i][j][reg];
        else        Cb[idx] = (bf16)acc[i][j][reg];
      }
    }
}

// ---------------------------------------------------------------- depthwise causal conv + silu + split
__global__ void conv_silu_k(const bf16* __restrict__ proj,
                            const float* __restrict__ conv_w,
                            const float* __restrict__ conv_b,
                            bf16* __restrict__ xconv,
                            bf16* __restrict__ Bmb, bf16* __restrict__ Cmb)
{
  int ch = blockIdx.x * 256 + threadIdx.x;
  if (ch >= CONVD) return;
  long bl = blockIdx.y;
  int l = (int)(bl & (LQ - 1));
  float acc = conv_b[ch];
  #pragma unroll
  for (int t = 0; t < 4; ++t) {
    int ls = l - 3 + t;
    if (ls >= 0)
      acc += (float)proj[(bl - 3 + t) * PROJP + INTER + ch] * conv_w[ch * 4 + t];
  }
  float y = siluf(acc);
  if (ch < INTER)            xconv[bl * INTER + ch] = (bf16)y;
  else if (ch < INTER + NS)  Bmb[bl * NS + (ch - INTER)] = (bf16)y;
  else                       Cmb[bl * NS + (ch - INTER - NS)] = (bf16)y;
}

// ---------------------------------------------------------------- dt softplus + per-chunk cumsum of dA
__global__ __launch_bounds__(CS) void dt_prep_k(
    const bf16* __restrict__ proj, const float* __restrict__ dt_bias,
    const float* __restrict__ A_log,
    float* __restrict__ dtv, float* __restrict__ acum, float* __restrict__ cdec)
{
  int bx = blockIdx.x;          // (b*NH + h)*NC + ci
  int ci = bx & 7;
  int bh = bx >> 3;
  int h  = bh & 63;
  int b  = bh >> 6;
  int i  = threadIdx.x;
  long pos = (long)b * LQ + ci * CS + i;
  float draw = (float)proj[pos * PROJP + INTER + CONVD + h] + dt_bias[h];
  float dv = draw > 20.f ? draw : log1pf(expf(draw));
  float Ah = -expf(A_log[h]);
  __shared__ float s[CS];
  s[i] = dv * Ah;
  __syncthreads();
  for (int off = 1; off < CS; off <<= 1) {
    float t = (i >= off) ? s[i - off] : 0.f;
    __syncthreads();
    s[i] += t;
    __syncthreads();
  }
  long base = (long)bx * CS;
  dtv[base + i]  = dv;
  acum[base + i] = s[i];
  if (i == 0) cdec[bx] = expf(s[CS - 1]);
}

// ---------------------------------------------------------------- G[i][j] = C_i . B_j via MFMA (G=1, head-independent)
__global__ __launch_bounds__(256) void gmat_k(
    const bf16* __restrict__ Cmb, const bf16* __restrict__ Bmb, float* __restrict__ Gnt)
{
  int q  = blockIdx.x;              // quadrant: ti=q>>1, tj=q&1 (128x128 each)
  int bc = blockIdx.y;              // b*NC + ci
  long bl0 = (long)(bc >> 3) * LQ + (bc & 7) * CS;
  int wave = threadIdx.x >> 6, lane = threadIdx.x & 63;
  int quad = lane >> 4, r16 = lane & 15;
  int i0 = (q >> 1) * 128 + (wave >> 1) * 64;
  int j0 = (q & 1)  * 128 + (wave & 1)  * 64;

  f32x4 acc[4][4] = {};
  #pragma unroll
  for (int kt = 0; kt < 4; ++kt) {
    int k0 = kt * 32 + quad * 8;
    bf16x8 af[4], bfv[4];
    #pragma unroll
    for (int it = 0; it < 4; ++it)
      af[it] = *(const bf16x8*)&Cmb[(bl0 + i0 + it * 16 + r16) * NS + k0];
    #pragma unroll
    for (int nt = 0; nt < 4; ++nt)
      bfv[nt] = *(const bf16x8*)&Bmb[(bl0 + j0 + nt * 16 + r16) * NS + k0];
    #pragma unroll
    for (int it = 0; it < 4; ++it)
      #pragma unroll
      for (int nt = 0; nt < 4; ++nt)
        acc[it][nt] = __builtin_amdgcn_mfma_f32_16x16x32_bf16(af[it], bfv[nt], acc[it][nt], 0, 0, 0);
  }
  #pragma unroll
  for (int it = 0; it < 4; ++it)
    #pragma unroll
    for (int nt = 0; nt < 4; ++nt)
      #pragma unroll
      for (int reg = 0; reg < 4; ++reg) {
        int i = i0 + it * 16 + quad * 4 + reg;
        int j = j0 + nt * 16 + r16;
        Gnt[((long)bc * CS + i) * CS + j] = acc[it][nt][reg];
      }
}

// ---------------------------------------------------------------- chunk states (HD x NS per b,c,h) -> bf16
__global__ __launch_bounds__(256) void states_k(
    const bf16* __restrict__ xconv, const bf16* __restrict__ Bmb,
    const float* __restrict__ dtv, const float* __restrict__ acum,
    bf16* __restrict__ states)
{
  int bx = blockIdx.x;          // bc*NH + h
  int h = bx & 63, bc = bx >> 6;
  int b = bc >> 3, ci = bc & 7;
  long bl0 = (long)b * LQ + ci * CS;
  long abase = ((long)(b * NH + h) * NC + ci) * CS;
  int t = threadIdx.x;
  __shared__ float ac_s[CS];
  __shared__ float ws_s[CS];
  __shared__ float xw[64][64];
  __shared__ float Bl[64][NS];
  ac_s[t] = acum[abase + t];
  __syncthreads();
  float alast = ac_s[CS - 1];
  ws_s[t] = expf(alast - ac_s[t]) * dtv[abase + t];
  int p = t & 63, nb = t >> 6;
  float accv[32] = {};
  for (int jt = 0; jt < 4; ++jt) {
    __syncthreads();
    for (int r = 0; r < 16; ++r) {
      int jj = (t >> 6) + r * 4;
      xw[jj][p] = (float)xconv[(bl0 + jt * 64 + jj) * INTER + h * HD + p] * ws_s[jt * 64 + jj];
    }
    for (int r = 0; r < 32; ++r) {
      int idx = t + r * 256;
      int jj = idx >> 7, n = idx & 127;
      Bl[jj][n] = (float)Bmb[(bl0 + jt * 64 + jj) * NS + n];
    }
    __syncthreads();
    for (int jj = 0; jj < 64; ++jj) {
      float xv = xw[jj][p];
      #pragma unroll
      for (int n0 = 0; n0 < 32; ++n0)
        accv[n0] += xv * Bl[jj][nb * 32 + n0];
    }
  }
  long sb = ((long)bx * HD + p) * NS + nb * 32;
  #pragma unroll
  for (int n0 = 0; n0 < 32; ++n0) states[sb + n0] = (bf16)accv[n0];
}

// ---------------------------------------------------------------- inter-chunk scan, IN PLACE (st -> prev)
__global__ void scan_k(bf16* __restrict__ st, const float* __restrict__ cdec)
{
  long t = (long)blockIdx.x * 256 + threadIdx.x;  // (b,h,p,n)
  int n = (int)(t & 127);
  int p = (int)((t >> 7) & 63);
  int h = (int)((t >> 13) & 63);
  int b = (int)(t >> 19);
  float carry = 0.f;
  for (int ci = 0; ci < NC; ++ci) {
    long idx = (((long)(b * NC + ci) * NH + h) * HD + p) * NS + n;
    float v = (float)st[idx];
    st[idx] = (bf16)carry;
    carry = cdec[(b * NH + h) * NC + ci] * carry + v;
  }
}

// ---------------------------------------------------------------- fused Ydiag+Yoff+D*x via MFMA  (Y aliases xconv)
// Per (bc,h):  Y[i][p] = sum_{k<384} A[i][k]*Bop[k][p] + Dh*X[i][p]
//   A[i][j]     = (j<=i) ? G[i][j]*dt_j*exp2(a2_i-a2_j) : 0   (j<256, in-register)
//   A[i][256+n] = exp(a_i)*C[i][n]
//   Bop[j][p]   = X[j][p] (j<256);  Bop[256+n][p] = prev[n][p]
#define XTP 392   /* padded row length (bf16) for Xt: 384+8, keeps 16B alignment */
__global__ __launch_bounds__(256) void ymix_k(
    const bf16* __restrict__ xconv, const float* __restrict__ Gnt,
    const bf16* __restrict__ prev, const bf16* __restrict__ Cmb,
    const float* __restrict__ dtv, const float* __restrict__ acum,
    const float* __restrict__ Dp, bf16* __restrict__ Y)
{
  int bx = blockIdx.x;          // bc*NH + h
  int h = bx & 63, bc = bx >> 6;
  int b = bc >> 3, ci = bc & 7;
  long bl0 = (long)b * LQ + ci * CS;
  long abase = ((long)(b * NH + h) * NC + ci) * CS;
  int t = threadIdx.x;
  int wave = t >> 6, lane = t & 63;
  int quad = lane >> 4, r16 = lane & 15;
  int iw = wave * 64;

  __shared__ bf16 Xt[64][XTP];          // [p][k]: k<256 = X^T, k>=256 = prev^T
  __shared__ float a2s[CS], dts[CS], eas[CS];

  {
    float ac = acum[abase + t];
    a2s[t] = ac * LOG2E;
    dts[t] = dtv[abase + t];
    eas[t] = expf(ac);
  }
  // stage X^T: Xt[p][j] = X[bl0+j][h*HD+p]
  {
    int col = t & 63, grp = t >> 6;
    for (int r = 0; r < 64; ++r) {
      int j = grp * 64 + r;
      Xt[col][j] = xconv[(bl0 + j) * INTER + h * HD + col];
    }
  }
  // stage prev^T: Xt[p][256+n] = prev[bx][p][n]
  for (int r = 0; r < 32; ++r) {
    int idx = t + r * 256;
    int n = idx & 127, p = idx >> 7;
    Xt[p][256 + n] = prev[((long)bx * HD + p) * NS + n];
  }
  __syncthreads();

  f32x4 acc[4][4] = {};

  for (int kt = 0; kt < 12; ++kt) {
    int k0 = kt * 32;
    bool cpart = (k0 >= 256);
    if (!cpart && k0 > iw + 63) continue;   // whole k-tile above diagonal for this wave

    bf16x8 bfrag[4];
    #pragma unroll
    for (int nt = 0; nt < 4; ++nt)
      bfrag[nt] = *(const bf16x8*)&Xt[nt * 16 + r16][k0 + quad * 8];

    if (!cpart) {
      int j0 = k0 + quad * 8;
      float dt8[8], a28[8];
      *(float4*)&dt8[0] = *(const float4*)&dts[j0];
      *(float4*)&dt8[4] = *(const float4*)&dts[j0 + 4];
      *(float4*)&a28[0] = *(const float4*)&a2s[j0];
      *(float4*)&a28[4] = *(const float4*)&a2s[j0 + 4];
      #pragma unroll
      for (int it = 0; it < 4; ++it) {
        if (k0 > iw + it * 16 + 15) continue;   // zero tile
        int i = iw + it * 16 + r16;
        float a2i = a2s[i];
        const float* gp = &Gnt[((long)bc * CS + i) * CS + j0];
        float g[8];
        *(float4*)&g[0] = *(const float4*)gp;
        *(float4*)&g[4] = *(const float4*)(gp + 4);
        bf16x8 af;
        #pragma unroll
        for (int jj = 0; jj < 8; ++jj) {
          float v = g[jj] * dt8[jj] * exp2f(a2i - a28[jj]);
          v = (j0 + jj <= i) ? v : 0.f;
          af[jj] = (bf16)v;
        }
        #pragma unroll
        for (int nt = 0; nt < 4; ++nt)
          acc[it][nt] = __builtin_amdgcn_mfma_f32_16x16x32_bf16(af, bfrag[nt], acc[it][nt], 0, 0, 0);
      }
    } else {
      int n0 = k0 - 256 + quad * 8;
      #pragma unroll
      for (int it = 0; it < 4; ++it) {
        int i = iw + it * 16 + r16;
        float e = eas[i];
        bf16x8 cv = *(const bf16x8*)&Cmb[(bl0 + i) * NS + n0];
        bf16x8 af;
        #pragma unroll
        for (int jj = 0; jj < 8; ++jj)
          af[jj] = (bf16)(e * (float)cv[jj]);
        #pragma unroll
        for (int nt = 0; nt < 4; ++nt)
          acc[it][nt] = __builtin_amdgcn_mfma_f32_16x16x32_bf16(af, bfrag[nt], acc[it][nt], 0, 0, 0);
      }
    }
  }

  float Dh = Dp[h];
  #pragma unroll
  for (int it = 0; it < 4; ++it)
    #pragma unroll
    for (int nt = 0; nt < 4; ++nt) {
      int i0 = iw + it * 16 + quad * 4;
      int p  = nt * 16 + r16;
      bf16x4 xv = *(const bf16x4*)&Xt[p][i0];
      #pragma unroll
      for (int reg = 0; reg < 4; ++reg) {
        float v = acc[it][nt][reg] + Dh * (float)xv[reg];
        Y[(bl0 + i0 + reg) * INTER + h * HD + p] = (bf16)v;
      }
    }
}

// ---------------------------------------------------------------- gate*silu + RMS norm, IN PLACE
__global__ __launch_bounds__(256) void norm_k(
    bf16* __restrict__ Y, const bf16* __restrict__ proj,
    const float* __restrict__ norm_w)
{
  long bl = blockIdx.x;
  int t = threadIdx.x;
  __shared__ float yb[INTER];
  __shared__ float red[256];
  float ss = 0.f;
  for (int r = 0; r < 16; ++r) {
    int ch = t + r * 256;
    float g = (float)proj[bl * PROJP + ch];
    float yv = (float)Y[bl * INTER + ch] * siluf(g);
    yb[ch] = yv;
    ss += yv * yv;
  }
  red[t] = ss;
  __syncthreads();
  for (int s = 128; s > 0; s >>= 1) {
    if (t < s) red[t] += red[t + s];
    __syncthreads();
  }
  float scale = rsqrtf(red[0] / (float)INTER + EPSF);
  for (int r = 0; r < 16; ++r) {
    int ch = t + r * 256;
    Y[bl * INTER + ch] = (bf16)(yb[ch] * scale * norm_w[ch]);
  }
}

// ---------------------------------------------------------------- launch
extern "C" void kernel_launch(void* const* d_in, const int* in_sizes, int n_in,
                              void* d_out, int out_size, void* d_ws, size_t ws_size,
                              hipStream_t stream)
{
  (void)in_sizes; (void)n_in; (void)out_size; (void)ws_size;
  const float* hidden  = (const float*)d_in[0];
  const float* W_in    = (const float*)d_in[1];
  const float* conv_w  = (const float*)d_in[2];
  const float* conv_b  = (const float*)d_in[3];
  const float* dt_bias = (const float*)d_in[4];
  const float* A_log   = (const float*)d_in[5];
  const float* Dp      = (const float*)d_in[6];
  const float* norm_w  = (const float*)d_in[7];
  const float* W_out   = (const float*)d_in[8];
  float* out = (float*)d_out;

  // ---- workspace layout with lifetime-based aliasing (peak ~123 MiB)
  char* ws    = (char*)d_ws;
  bf16* projb = (bf16*)(ws);                         // 70,254,592  [gemm1 .. norm]
  char* base2 = ws + 70254592;
  bf16*  hb    = (bf16*)(base2);                     // 16,777,216  [stage1 only]
  bf16*  winb  = (bf16*)(base2 + 16777216);          // 35,127,296  [stage1 only]
  bf16*  xconv = (bf16*)(base2);                     // 33,554,432  [conv .. ymix] = Y
  bf16*  st    = (bf16*)(base2 + 33554432);          // 16,777,216  [states .. ymix]
  float* Gnt   = (float*)(base2 + 50331648);         //  4,194,304
  bf16*  Bmb   = (bf16*)(base2 + 54525952);          //  1,048,576
  bf16*  Cmb   = (bf16*)(base2 + 55574528);          //  1,048,576
  float* dtv   = (float*)(base2 + 56623104);         //  1,048,576
  float* acum  = (float*)(base2 + 57671680);         //  1,048,576
  float* cdec  = (float*)(base2 + 58720256);         //      4,096
  bf16*  Yb    = xconv;                              // alias (disjoint per-block tiles)
  bf16*  woutb = st;                                 // alias st (dead after ymix), exact 16 MiB

  // stage 1: casts + in-projection GEMM
  cast4_k<<<dim3((unsigned)((MTOT * (long)DMODEL / 4 + 255) / 256)), 256, 0, stream>>>(
      hidden, hb, (long)MTOT * DMODEL / 4);
  cast_pad_win_k<<<dim3((unsigned)(((long)PROJP * (DMODEL / 4) + 255) / 256)), 256, 0, stream>>>(
      W_in, winb);
  gemm_bt<<<dim3(PROJP / BN, MTOT / BM), 256, 0, stream>>>(
      hb, winb, projb, nullptr, MTOT, PROJP, DMODEL, 0);

  // stage 2: conv + SSD
  conv_silu_k<<<dim3(CONVD / 256, MTOT), 256, 0, stream>>>(
      projb, conv_w, conv_b, xconv, Bmb, Cmb);
  dt_prep_k<<<dim3(BQ * NH * NC), CS, 0, stream>>>(
      projb, dt_bias, A_log, dtv, acum, cdec);
  gmat_k<<<dim3(4, BQ * NC), 256, 0, stream>>>(Cmb, Bmb, Gnt);
  states_k<<<dim3(BQ * NC * NH), 256, 0, stream>>>(xconv, Bmb, dtv, acum, st);
  scan_k<<<dim3(BQ * NH * HD * NS / 256), 256, 0, stream>>>(st, cdec);
  ymix_k<<<dim3(BQ * NC * NH), 256, 0, stream>>>(
      xconv, Gnt, st, Cmb, dtv, acum, Dp, Yb);

  // stage 3: norm + out-projection GEMM
  cast4_k<<<dim3((unsigned)((DMODEL * (long)INTER / 4 + 255) / 256)), 256, 0, stream>>>(
      W_out, woutb, (long)DMODEL * INTER / 4);
  norm_k<<<dim3(MTOT), 256, 0, stream>>>(Yb, projb, norm_w);
  gemm_bt<<<dim3(DMODEL / BN, MTOT / BM), 256, 0, stream>>>(
      Yb, woutb, nullptr, out, MTOT, DMODEL, INTER, 1);
}

// Round 4
// 705.376 us; speedup vs baseline: 2.4998x; 1.1376x over previous
//
#include <hip/hip_runtime.h>
#include <cstdint>

typedef __bf16 bf16;
typedef __bf16 bf16x8 __attribute__((ext_vector_type(8)));
typedef __bf16 bf16x4 __attribute__((ext_vector_type(4)));
typedef float  f32x4  __attribute__((ext_vector_type(4)));

#define BQ     2
#define LQ     2048
#define DMODEL 2048
#define INTER  4096
#define NH     64
#define HD     64
#define NS     128
#define CS     256
#define NC     8
#define CONVD  4352
#define PROJD  8512
#define PROJP  8576   /* padded to 128-multiple */
#define MTOT   4096   /* B*L */
#define EPSF   1e-5f
#define LOG2E  1.44269504088896f

// ---------------------------------------------------------------- utilities
__device__ __forceinline__ void async_ld16(const bf16* g, bf16* l) {
  __builtin_amdgcn_global_load_lds(
      (__attribute__((address_space(1))) void*)(uintptr_t)g,
      (__attribute__((address_space(3))) void*)l, 16, 0, 0);
}

__device__ __forceinline__ float siluf(float x) { return x / (1.f + expf(-x)); }

// ---------------------------------------------------------------- casts
__global__ void cast4_k(const float* __restrict__ in, bf16* __restrict__ out, long n4) {
  long i = (long)blockIdx.x * 256 + threadIdx.x;
  if (i >= n4) return;
  float4 v = ((const float4*)in)[i];
  bf16x4 o; o[0] = (bf16)v.x; o[1] = (bf16)v.y; o[2] = (bf16)v.z; o[3] = (bf16)v.w;
  ((bf16x4*)out)[i] = o;
}

__global__ void cast_pad_win_k(const float* __restrict__ W, bf16* __restrict__ out) {
  long i = (long)blockIdx.x * 256 + threadIdx.x;       // over PROJP * (DMODEL/4)
  long tot = (long)PROJP * (DMODEL / 4);
  if (i >= tot) return;
  long row = i / (DMODEL / 4);
  long k4  = i % (DMODEL / 4);
  bf16x4 o;
  if (row < PROJD) {
    float4 v = ((const float4*)W)[row * (DMODEL / 4) + k4];
    o[0] = (bf16)v.x; o[1] = (bf16)v.y; o[2] = (bf16)v.z; o[3] = (bf16)v.w;
  } else {
    o[0] = o[1] = o[2] = o[3] = (bf16)0.f;
  }
  ((bf16x4*)out)[i] = o;
}

// ---------------------------------------------------------------- GEMM  C = A(MxK) * W(NxK)^T
#define BM 128
#define BN 128
#define BK 32

__global__ __launch_bounds__(256) void gemm_bt(
    const bf16* __restrict__ A, const bf16* __restrict__ W,
    bf16* __restrict__ Cb, float* __restrict__ Cf,
    int M, int Nn, int K, int outf32)
{
  __shared__ bf16 As[BM * BK];
  __shared__ bf16 Bs[BN * BK];
  const int tid  = threadIdx.x;
  const int wave = tid >> 6;
  const int lane = tid & 63;

  // group-of-8 swizzle along M: 8 consecutive blocks share one N-tile (W-panel
  // reused 8x back-to-back; 8 A-panels = 4 MB stay L2-resident across N-steps)
  int bxi, byi;
  {
    int b = blockIdx.y * gridDim.x + blockIdx.x;
    if ((gridDim.y & 7) == 0) {
      int gs = gridDim.x * 8;
      int g = b / gs, r = b % gs;
      byi = g * 8 + (r & 7);
      bxi = r >> 3;
    } else { bxi = blockIdx.x; byi = blockIdx.y; }
  }
  const long tm = (long)byi * BM;
  const long tn = (long)bxi * BN;
  const int wm = (wave >> 1) * 64;
  const int wn = (wave & 1) * 64;
  const int quad = lane >> 4;
  const int r16  = lane & 15;

  f32x4 acc[4][4] = {};

  for (long k0 = 0; k0 < K; k0 += BK) {
    __syncthreads();
    #pragma unroll
    for (int p = 0; p < 2; ++p) {
      int row = p * 64 + (tid >> 2);
      int kc  = (tid & 3) * 8;
      async_ld16(A + (tm + row) * K + k0 + kc, &As[(p * 256 + wave * 64) * 8]);
      async_ld16(W + (tn + row) * K + k0 + kc, &Bs[(p * 256 + wave * 64) * 8]);
    }
    __syncthreads();
    bf16x8 af[4], bfr[4];
    #pragma unroll
    for (int i = 0; i < 4; ++i)
      af[i] = *(const bf16x8*)&As[(wm + i * 16 + r16) * BK + quad * 8];
    #pragma unroll
    for (int j = 0; j < 4; ++j)
      bfr[j] = *(const bf16x8*)&Bs[(wn + j * 16 + r16) * BK + quad * 8];
    #pragma unroll
    for (int i = 0; i < 4; ++i)
      #pragma unroll
      for (int j = 0; j < 4; ++j)
        acc[i][j] = __builtin_amdgcn_mfma_f32_16x16x32_bf16(af[i], bfr[j], acc[i][j], 0, 0, 0);
  }

  #pragma unroll
  for (int i = 0; i < 4; ++i)
    #pragma unroll
    for (int j = 0; j < 4; ++j) {
      long r0 = tm + wm + i * 16 + quad * 4;
      long cc = tn + wn + j * 16 + r16;
      #pragma unroll
      for (int reg = 0; reg < 4; ++reg) {
        long idx = (r0 + reg) * (long)Nn + cc;
        if (outf32) Cf[idx] = acc[i][j][reg];
        else        Cb[idx] = (bf16)acc[i][j][reg];
      }
    }
}

// ---------------------------------------------------------------- depthwise causal conv + silu + split (+ B^T copy)
__global__ void conv_silu_k(const bf16* __restrict__ proj,
                            const float* __restrict__ conv_w,
                            const float* __restrict__ conv_b,
                            bf16* __restrict__ xconv,
                            bf16* __restrict__ Bmb, bf16* __restrict__ Cmb,
                            bf16* __restrict__ Bt)
{
  int ch = blockIdx.x * 256 + threadIdx.x;
  if (ch >= CONVD) return;
  long bl = blockIdx.y;
  int l = (int)(bl & (LQ - 1));
  float acc = conv_b[ch];
  #pragma unroll
  for (int t = 0; t < 4; ++t) {
    int ls = l - 3 + t;
    if (ls >= 0)
      acc += (float)proj[(bl - 3 + t) * PROJP + INTER + ch] * conv_w[ch * 4 + t];
  }
  float y = siluf(acc);
  if (ch < INTER) {
    xconv[bl * INTER + ch] = (bf16)y;
  } else if (ch < INTER + NS) {
    int n = ch - INTER;
    Bmb[bl * NS + n] = (bf16)y;
    int b = (int)(bl >> 11), ci = l >> 8, j = l & 255;
    Bt[(((long)(b * NC + ci) * NS) + n) * CS + j] = (bf16)y;
  } else {
    Cmb[bl * NS + (ch - INTER - NS)] = (bf16)y;
  }
}

// ---------------------------------------------------------------- dt softplus + per-chunk cumsum of dA
__global__ __launch_bounds__(CS) void dt_prep_k(
    const bf16* __restrict__ proj, const float* __restrict__ dt_bias,
    const float* __restrict__ A_log,
    float* __restrict__ dtv, float* __restrict__ acum, float* __restrict__ cdec)
{
  int bx = blockIdx.x;          // (b*NH + h)*NC + ci
  int ci = bx & 7;
  int bh = bx >> 3;
  int h  = bh & 63;
  int b  = bh >> 6;
  int i  = threadIdx.x;
  long pos = (long)b * LQ + ci * CS + i;
  float draw = (float)proj[pos * PROJP + INTER + CONVD + h] + dt_bias[h];
  float dv = draw > 20.f ? draw : log1pf(expf(draw));
  float Ah = -expf(A_log[h]);
  __shared__ float s[CS];
  s[i] = dv * Ah;
  __syncthreads();
  for (int off = 1; off < CS; off <<= 1) {
    float t = (i >= off) ? s[i - off] : 0.f;
    __syncthreads();
    s[i] += t;
    __syncthreads();
  }
  long base = (long)bx * CS;
  dtv[base + i]  = dv;
  acum[base + i] = s[i];
  if (i == 0) cdec[bx] = expf(s[CS - 1]);
}

// ---------------------------------------------------------------- G[i][j] = C_i . B_j via MFMA (G=1, head-independent)
__global__ __launch_bounds__(256) void gmat_k(
    const bf16* __restrict__ Cmb, const bf16* __restrict__ Bmb, float* __restrict__ Gnt)
{
  int q  = blockIdx.x;              // quadrant: ti=q>>1, tj=q&1 (128x128 each)
  int bc = blockIdx.y;              // b*NC + ci
  long bl0 = (long)(bc >> 3) * LQ + (bc & 7) * CS;
  int wave = threadIdx.x >> 6, lane = threadIdx.x & 63;
  int quad = lane >> 4, r16 = lane & 15;
  int i0 = (q >> 1) * 128 + (wave >> 1) * 64;
  int j0 = (q & 1)  * 128 + (wave & 1)  * 64;

  f32x4 acc[4][4] = {};
  #pragma unroll
  for (int kt = 0; kt < 4; ++kt) {
    int k0 = kt * 32 + quad * 8;
    bf16x8 af[4], bfv[4];
    #pragma unroll
    for (int it = 0; it < 4; ++it)
      af[it] = *(const bf16x8*)&Cmb[(bl0 + i0 + it * 16 + r16) * NS + k0];
    #pragma unroll
    for (int nt = 0; nt < 4; ++nt)
      bfv[nt] = *(const bf16x8*)&Bmb[(bl0 + j0 + nt * 16 + r16) * NS + k0];
    #pragma unroll
    for (int it = 0; it < 4; ++it)
      #pragma unroll
      for (int nt = 0; nt < 4; ++nt)
        acc[it][nt] = __builtin_amdgcn_mfma_f32_16x16x32_bf16(af[it], bfv[nt], acc[it][nt], 0, 0, 0);
  }
  #pragma unroll
  for (int it = 0; it < 4; ++it)
    #pragma unroll
    for (int nt = 0; nt < 4; ++nt)
      #pragma unroll
      for (int reg = 0; reg < 4; ++reg) {
        int i = i0 + it * 16 + quad * 4 + reg;
        int j = j0 + nt * 16 + r16;
        Gnt[((long)bc * CS + i) * CS + j] = acc[it][nt][reg];
      }
}

// ---------------------------------------------------------------- chunk states via MFMA: state[p][n] = sum_j (X[j][p]*w_j)*B[j][n]
__global__ __launch_bounds__(256) void states_k(
    const bf16* __restrict__ xconv, const bf16* __restrict__ Bt,
    const float* __restrict__ dtv, const float* __restrict__ acum,
    bf16* __restrict__ st)
{
  int bx = blockIdx.x;          // bc*NH + h
  int h = bx & 63, bc = bx >> 6;
  int b = bc >> 3, ci = bc & 7;
  long bl0 = (long)b * LQ + ci * CS;
  long abase = ((long)(b * NH + h) * NC + ci) * CS;
  int t = threadIdx.x;
  int wave = t >> 6, lane = t & 63, quad = lane >> 4, r16 = lane & 15;

  __shared__ bf16 Xt[64][264];
  __shared__ float ws[CS];
  __shared__ float ac_s[CS];
  ac_s[t] = acum[abase + t];
  __syncthreads();
  float alast = ac_s[CS - 1];
  ws[t] = expf(alast - ac_s[t]) * dtv[abase + t];
  // stage X^T (coalesced: lanes span p)
  {
    int col = t & 63, grp = t >> 6;
    for (int r = 0; r < 64; ++r) {
      int j = grp * 64 + r;
      Xt[col][j] = xconv[(bl0 + j) * INTER + h * HD + col];
    }
  }
  __syncthreads();

  const bf16* btb = &Bt[(long)bc * NS * CS];
  f32x4 acc[8] = {};
  int p = wave * 16 + r16;
  #pragma unroll
  for (int kt = 0; kt < 8; ++kt) {
    int k0 = kt * 32 + quad * 8;
    bf16x8 xv = *(const bf16x8*)&Xt[p][k0];
    float w8[8];
    *(float4*)&w8[0] = *(const float4*)&ws[k0];
    *(float4*)&w8[4] = *(const float4*)&ws[k0 + 4];
    bf16x8 af;
    #pragma unroll
    for (int jj = 0; jj < 8; ++jj) af[jj] = (bf16)((float)xv[jj] * w8[jj]);
    #pragma unroll
    for (int nt = 0; nt < 8; ++nt) {
      bf16x8 bfv = *(const bf16x8*)&btb[(nt * 16 + r16) * CS + k0];
      acc[nt] = __builtin_amdgcn_mfma_f32_16x16x32_bf16(af, bfv, acc[nt], 0, 0, 0);
    }
  }
  #pragma unroll
  for (int nt = 0; nt < 8; ++nt)
    #pragma unroll
    for (int reg = 0; reg < 4; ++reg) {
      int prow = wave * 16 + quad * 4 + reg;
      int n = nt * 16 + r16;
      st[((long)bx * HD + prow) * NS + n] = (bf16)acc[nt][reg];
    }
}

// ---------------------------------------------------------------- inter-chunk scan, IN PLACE (st -> prev)
__global__ void scan_k(bf16* __restrict__ st, const float* __restrict__ cdec)
{
  long t = (long)blockIdx.x * 256 + threadIdx.x;  // (b,h,p,n)
  int n = (int)(t & 127);
  int p = (int)((t >> 7) & 63);
  int h = (int)((t >> 13) & 63);
  int b = (int)(t >> 19);
  float carry = 0.f;
  for (int ci = 0; ci < NC; ++ci) {
    long idx = (((long)(b * NC + ci) * NH + h) * HD + p) * NS + n;
    float v = (float)st[idx];
    st[idx] = (bf16)carry;
    carry = cdec[(b * NH + h) * NC + ci] * carry + v;
  }
}

// ---------------------------------------------------------------- fused Ydiag+Yoff+D*x via MFMA  (Y aliases xconv)
#define XTP 392   /* padded row length (bf16) for Xt: 384+8, keeps 16B alignment */
__global__ __launch_bounds__(256) void ymix_k(
    const bf16* __restrict__ xconv, const float* __restrict__ Gnt,
    const bf16* __restrict__ prev, const bf16* __restrict__ Cmb,
    const float* __restrict__ dtv, const float* __restrict__ acum,
    const float* __restrict__ Dp, bf16* __restrict__ Y)
{
  int bx = blockIdx.x;          // bc*NH + h
  int h = bx & 63, bc = bx >> 6;
  int b = bc >> 3, ci = bc & 7;
  long bl0 = (long)b * LQ + ci * CS;
  long abase = ((long)(b * NH + h) * NC + ci) * CS;
  int t = threadIdx.x;
  int wave = t >> 6, lane = t & 63;
  int quad = lane >> 4, r16 = lane & 15;
  int iw = wave * 64;

  __shared__ bf16 Xt[64][XTP];          // [p][k]: k<256 = X^T, k>=256 = prev^T
  __shared__ float a2s[CS], dts[CS], eas[CS];

  {
    float ac = acum[abase + t];
    a2s[t] = ac * LOG2E;
    dts[t] = dtv[abase + t];
    eas[t] = expf(ac);
  }
  {
    int col = t & 63, grp = t >> 6;
    for (int r = 0; r < 64; ++r) {
      int j = grp * 64 + r;
      Xt[col][j] = xconv[(bl0 + j) * INTER + h * HD + col];
    }
  }
  for (int r = 0; r < 32; ++r) {
    int idx = t + r * 256;
    int n = idx & 127, p = idx >> 7;
    Xt[p][256 + n] = prev[((long)bx * HD + p) * NS + n];
  }
  __syncthreads();

  f32x4 acc[4][4] = {};

  for (int kt = 0; kt < 12; ++kt) {
    int k0 = kt * 32;
    bool cpart = (k0 >= 256);
    if (!cpart && k0 > iw + 63) continue;   // whole k-tile above diagonal for this wave

    bf16x8 bfrag[4];
    #pragma unroll
    for (int nt = 0; nt < 4; ++nt)
      bfrag[nt] = *(const bf16x8*)&Xt[nt * 16 + r16][k0 + quad * 8];

    if (!cpart) {
      int j0 = k0 + quad * 8;
      float dt8[8], a28[8];
      *(float4*)&dt8[0] = *(const float4*)&dts[j0];
      *(float4*)&dt8[4] = *(const float4*)&dts[j0 + 4];
      *(float4*)&a28[0] = *(const float4*)&a2s[j0];
      *(float4*)&a28[4] = *(const float4*)&a2s[j0 + 4];
      #pragma unroll
      for (int it = 0; it < 4; ++it) {
        if (k0 > iw + it * 16 + 15) continue;   // zero tile
        int i = iw + it * 16 + r16;
        float a2i = a2s[i];
        const float* gp = &Gnt[((long)bc * CS + i) * CS + j0];
        float g[8];
        *(float4*)&g[0] = *(const float4*)gp;
        *(float4*)&g[4] = *(const float4*)(gp + 4);
        bf16x8 af;
        #pragma unroll
        for (int jj = 0; jj < 8; ++jj) {
          float v = g[jj] * dt8[jj] * exp2f(a2i - a28[jj]);
          v = (j0 + jj <= i) ? v : 0.f;
          af[jj] = (bf16)v;
        }
        #pragma unroll
        for (int nt = 0; nt < 4; ++nt)
          acc[it][nt] = __builtin_amdgcn_mfma_f32_16x16x32_bf16(af, bfrag[nt], acc[it][nt], 0, 0, 0);
      }
    } else {
      int n0 = k0 - 256 + quad * 8;
      #pragma unroll
      for (int it = 0; it < 4; ++it) {
        int i = iw + it * 16 + r16;
        float e = eas[i];
        bf16x8 cv = *(const bf16x8*)&Cmb[(bl0 + i) * NS + n0];
        bf16x8 af;
        #pragma unroll
        for (int jj = 0; jj < 8; ++jj)
          af[jj] = (bf16)(e * (float)cv[jj]);
        #pragma unroll
        for (int nt = 0; nt < 4; ++nt)
          acc[it][nt] = __builtin_amdgcn_mfma_f32_16x16x32_bf16(af, bfrag[nt], acc[it][nt], 0, 0, 0);
      }
    }
  }

  float Dh = Dp[h];
  #pragma unroll
  for (int it = 0; it < 4; ++it)
    #pragma unroll
    for (int nt = 0; nt < 4; ++nt) {
      int i0 = iw + it * 16 + quad * 4;
      int p  = nt * 16 + r16;
      bf16x4 xv = *(const bf16x4*)&Xt[p][i0];
      #pragma unroll
      for (int reg = 0; reg < 4; ++reg) {
        float v = acc[it][nt][reg] + Dh * (float)xv[reg];
        Y[(bl0 + i0 + reg) * INTER + h * HD + p] = (bf16)v;
      }
    }
}

// ---------------------------------------------------------------- gate*silu + RMS norm, IN PLACE
__global__ __launch_bounds__(256) void norm_k(
    bf16* __restrict__ Y, const bf16* __restrict__ proj,
    const float* __restrict__ norm_w)
{
  long bl = blockIdx.x;
  int t = threadIdx.x;
  __shared__ float yb[INTER];
  __shared__ float red[256];
  float ss = 0.f;
  for (int r = 0; r < 16; ++r) {
    int ch = t + r * 256;
    float g = (float)proj[bl * PROJP + ch];
    float yv = (float)Y[bl * INTER + ch] * siluf(g);
    yb[ch] = yv;
    ss += yv * yv;
  }
  red[t] = ss;
  __syncthreads();
  for (int s = 128; s > 0; s >>= 1) {
    if (t < s) red[t] += red[t + s];
    __syncthreads();
  }
  float scale = rsqrtf(red[0] / (float)INTER + EPSF);
  for (int r = 0; r < 16; ++r) {
    int ch = t + r * 256;
    Y[bl * INTER + ch] = (bf16)(yb[ch] * scale * norm_w[ch]);
  }
}

// ---------------------------------------------------------------- launch
extern "C" void kernel_launch(void* const* d_in, const int* in_sizes, int n_in,
                              void* d_out, int out_size, void* d_ws, size_t ws_size,
                              hipStream_t stream)
{
  (void)in_sizes; (void)n_in; (void)out_size; (void)ws_size;
  const float* hidden  = (const float*)d_in[0];
  const float* W_in    = (const float*)d_in[1];
  const float* conv_w  = (const float*)d_in[2];
  const float* conv_b  = (const float*)d_in[3];
  const float* dt_bias = (const float*)d_in[4];
  const float* A_log   = (const float*)d_in[5];
  const float* Dp      = (const float*)d_in[6];
  const float* norm_w  = (const float*)d_in[7];
  const float* W_out   = (const float*)d_in[8];
  float* out = (float*)d_out;

  // ---- workspace layout with lifetime-based aliasing (peak ~124.7 MiB)
  char* ws    = (char*)d_ws;
  bf16* projb = (bf16*)(ws);                         // 70,254,592  [gemm1 .. norm]
  char* base2 = ws + 70254592;
  bf16*  hb    = (bf16*)(base2);                     // 16,777,216  [stage1 only]
  bf16*  winb  = (bf16*)(base2 + 16777216);          // 35,127,296  [stage1 only]
  bf16*  xconv = (bf16*)(base2);                     // 33,554,432  [conv .. ymix] = Y
  bf16*  st    = (bf16*)(base2 + 33554432);          // 16,777,216  [states .. ymix]
  float* Gnt   = (float*)(base2 + 50331648);         //  4,194,304
  bf16*  Bmb   = (bf16*)(base2 + 54525952);          //  1,048,576
  bf16*  Cmb   = (bf16*)(base2 + 55574528);          //  1,048,576
  float* dtv   = (float*)(base2 + 56623104);         //  1,048,576
  float* acum  = (float*)(base2 + 57671680);         //  1,048,576
  float* cdec  = (float*)(base2 + 58720256);         //      4,096
  bf16*  Bt    = (bf16*)(base2 + 58724352);          //  1,048,576 (B transposed per chunk)
  bf16*  Yb    = xconv;                              // alias (disjoint per-block tiles)
  bf16*  woutb = st;                                 // alias st (dead after ymix), exact 16 MiB

  // stage 1: casts + in-projection GEMM
  cast4_k<<<dim3((unsigned)((MTOT * (long)DMODEL / 4 + 255) / 256)), 256, 0, stream>>>(
      hidden, hb, (long)MTOT * DMODEL / 4);
  cast_pad_win_k<<<dim3((unsigned)(((long)PROJP * (DMODEL / 4) + 255) / 256)), 256, 0, stream>>>(
      W_in, winb);
  gemm_bt<<<dim3(PROJP / BN, MTOT / BM), 256, 0, stream>>>(
      hb, winb, projb, nullptr, MTOT, PROJP, DMODEL, 0);

  // stage 2: conv + SSD
  conv_silu_k<<<dim3(CONVD / 256, MTOT), 256, 0, stream>>>(
      projb, conv_w, conv_b, xconv, Bmb, Cmb, Bt);
  dt_prep_k<<<dim3(BQ * NH * NC), CS, 0, stream>>>(
      projb, dt_bias, A_log, dtv, acum, cdec);
  gmat_k<<<dim3(4, BQ * NC), 256, 0, stream>>>(Cmb, Bmb, Gnt);
  states_k<<<dim3(BQ * NC * NH), 256, 0, stream>>>(xconv, Bt, dtv, acum, st);
  scan_k<<<dim3(BQ * NH * HD * NS / 256), 256, 0, stream>>>(st, cdec);
  ymix_k<<<dim3(BQ * NC * NH), 256, 0, stream>>>(
      xconv, Gnt, st, Cmb, dtv, acum, Dp, Yb);

  // stage 3: norm + out-projection GEMM
  cast4_k<<<dim3((unsigned)((DMODEL * (long)INTER / 4 + 255) / 256)), 256, 0, stream>>>(
      W_out, woutb, (long)DMODEL * INTER / 4);
  norm_k<<<dim3(MTOT), 256, 0, stream>>>(Yb, projb, norm_w);
  gemm_bt<<<dim3(DMODEL / BN, MTOT / BM), 256, 0, stream>>>(
      Yb, woutb, nullptr, out, MTOT, DMODEL, INTER, 1);
}

// Round 5
// 686.102 us; speedup vs baseline: 2.5701x; 1.0281x over previous
//
#include <hip/hip_runtime.h>
#include <cstdint>

typedef __bf16 bf16;
typedef __bf16 bf16x8 __attribute__((ext_vector_type(8)));
typedef __bf16 bf16x4 __attribute__((ext_vector_type(4)));
typedef float  f32x4  __attribute__((ext_vector_type(4)));

#define BQ     2
#define LQ     2048
#define DMODEL 2048
#define INTER  4096
#define NH     64
#define HD     64
#define NS     128
#define CS     256
#define NC     8
#define CONVD  4352
#define PROJD  8512
#define PROJP  8576   /* padded to 128-multiple */
#define MTOT   4096   /* B*L */
#define EPSF   1e-5f
#define LOG2E  1.44269504088896f

// ---------------------------------------------------------------- utilities
__device__ __forceinline__ void async_ld16(const bf16* g, bf16* l) {
  __builtin_amdgcn_global_load_lds(
      (__attribute__((address_space(1))) void*)(uintptr_t)g,
      (__attribute__((address_space(3))) void*)l, 16, 0, 0);
}

__device__ __forceinline__ float siluf(float x) { return x / (1.f + expf(-x)); }

// ---------------------------------------------------------------- casts
__global__ void cast4_k(const float* __restrict__ in, bf16* __restrict__ out, long n4) {
  long i = (long)blockIdx.x * 256 + threadIdx.x;
  if (i >= n4) return;
  float4 v = ((const float4*)in)[i];
  bf16x4 o; o[0] = (bf16)v.x; o[1] = (bf16)v.y; o[2] = (bf16)v.z; o[3] = (bf16)v.w;
  ((bf16x4*)out)[i] = o;
}

__global__ void cast_pad_win_k(const float* __restrict__ W, bf16* __restrict__ out) {
  long i = (long)blockIdx.x * 256 + threadIdx.x;       // over PROJP * (DMODEL/4)
  long tot = (long)PROJP * (DMODEL / 4);
  if (i >= tot) return;
  long row = i / (DMODEL / 4);
  long k4  = i % (DMODEL / 4);
  bf16x4 o;
  if (row < PROJD) {
    float4 v = ((const float4*)W)[row * (DMODEL / 4) + k4];
    o[0] = (bf16)v.x; o[1] = (bf16)v.y; o[2] = (bf16)v.z; o[3] = (bf16)v.w;
  } else {
    o[0] = o[1] = o[2] = o[3] = (bf16)0.f;
  }
  ((bf16x4*)out)[i] = o;
}

// ---------------------------------------------------------------- GEMM  C = A(MxK) * W(NxK)^T
// BK=64, XOR-8 swizzled LDS: slot s of row r holds global k-group s^(r&7).
#define BM 128
#define BN 128
#define BK 64

__global__ __launch_bounds__(256) void gemm_bt(
    const bf16* __restrict__ A, const bf16* __restrict__ W,
    bf16* __restrict__ Cb, float* __restrict__ Cf,
    int M, int Nn, int K, int outf32)
{
  __shared__ bf16 As[BM * BK];   // 16 KB
  __shared__ bf16 Bs[BN * BK];   // 16 KB
  const int tid  = threadIdx.x;
  const int wave = tid >> 6;
  const int lane = tid & 63;

  // group-of-8 swizzle along M: 8 consecutive blocks share one N-tile
  int bxi, byi;
  {
    int b = blockIdx.y * gridDim.x + blockIdx.x;
    if ((gridDim.y & 7) == 0) {
      int gs = gridDim.x * 8;
      int g = b / gs, r = b % gs;
      byi = g * 8 + (r & 7);
      bxi = r >> 3;
    } else { bxi = blockIdx.x; byi = blockIdx.y; }
  }
  const long tm = (long)byi * BM;
  const long tn = (long)bxi * BN;
  const int wm = (wave >> 1) * 64;
  const int wn = (wave & 1) * 64;
  const int quad = lane >> 4;
  const int r16  = lane & 15;

  // staging coords: per round of 32 rows, this lane covers (row, k-group):
  const int srow = wave * 8 + (lane >> 3);        // + p*32
  const int scg  = (lane & 7) ^ (lane >> 3);      // XOR-swizzled k-group (16B units)

  f32x4 acc[4][4] = {};

  for (long k0 = 0; k0 < K; k0 += BK) {
    __syncthreads();
    #pragma unroll
    for (int p = 0; p < 4; ++p) {
      const bf16* ga = A + (tm + p * 32 + srow) * K + k0 + scg * 8;
      const bf16* gw = W + (tn + p * 32 + srow) * K + k0 + scg * 8;
      async_ld16(ga, &As[p * 2048 + wave * 512]);
      async_ld16(gw, &Bs[p * 2048 + wave * 512]);
    }
    __syncthreads();
    #pragma unroll
    for (int ks = 0; ks < 2; ++ks) {
      bf16x8 af[4], bfr[4];
      #pragma unroll
      for (int i = 0; i < 4; ++i) {
        int r = wm + i * 16 + r16;
        int slot = (ks * 4 + quad) ^ (r & 7);
        af[i] = *(const bf16x8*)&As[r * 64 + slot * 8];
      }
      #pragma unroll
      for (int j = 0; j < 4; ++j) {
        int r = wn + j * 16 + r16;
        int slot = (ks * 4 + quad) ^ (r & 7);
        bfr[j] = *(const bf16x8*)&Bs[r * 64 + slot * 8];
      }
      #pragma unroll
      for (int i = 0; i < 4; ++i)
        #pragma unroll
        for (int j = 0; j < 4; ++j)
          acc[i][j] = __builtin_amdgcn_mfma_f32_16x16x32_bf16(af[i], bfr[j], acc[i][j], 0, 0, 0);
    }
  }

  #pragma unroll
  for (int i = 0; i < 4; ++i)
    #pragma unroll
    for (int j = 0; j < 4; ++j) {
      long r0 = tm + wm + i * 16 + quad * 4;
      long cc = tn + wn + j * 16 + r16;
      #pragma unroll
      for (int reg = 0; reg < 4; ++reg) {
        long idx = (r0 + reg) * (long)Nn + cc;
        if (outf32) Cf[idx] = acc[i][j][reg];
        else        Cb[idx] = (bf16)acc[i][j][reg];
      }
    }
}

// ---------------------------------------------------------------- depthwise causal conv + silu + split (+ B^T copy)
__global__ void conv_silu_k(const bf16* __restrict__ proj,
                            const float* __restrict__ conv_w,
                            const float* __restrict__ conv_b,
                            bf16* __restrict__ xconv,
                            bf16* __restrict__ Bmb, bf16* __restrict__ Cmb,
                            bf16* __restrict__ Bt)
{
  int ch = blockIdx.x * 256 + threadIdx.x;
  if (ch >= CONVD) return;
  long bl = blockIdx.y;
  int l = (int)(bl & (LQ - 1));
  float acc = conv_b[ch];
  #pragma unroll
  for (int t = 0; t < 4; ++t) {
    int ls = l - 3 + t;
    if (ls >= 0)
      acc += (float)proj[(bl - 3 + t) * PROJP + INTER + ch] * conv_w[ch * 4 + t];
  }
  float y = siluf(acc);
  if (ch < INTER) {
    xconv[bl * INTER + ch] = (bf16)y;
  } else if (ch < INTER + NS) {
    int n = ch - INTER;
    Bmb[bl * NS + n] = (bf16)y;
    int b = (int)(bl >> 11), ci = l >> 8, j = l & 255;
    Bt[(((long)(b * NC + ci) * NS) + n) * CS + j] = (bf16)y;
  } else {
    Cmb[bl * NS + (ch - INTER - NS)] = (bf16)y;
  }
}

// ---------------------------------------------------------------- dt softplus + per-chunk cumsum of dA
__global__ __launch_bounds__(CS) void dt_prep_k(
    const bf16* __restrict__ proj, const float* __restrict__ dt_bias,
    const float* __restrict__ A_log,
    float* __restrict__ dtv, float* __restrict__ acum, float* __restrict__ cdec)
{
  int bx = blockIdx.x;          // (b*NH + h)*NC + ci
  int ci = bx & 7;
  int bh = bx >> 3;
  int h  = bh & 63;
  int b  = bh >> 6;
  int i  = threadIdx.x;
  long pos = (long)b * LQ + ci * CS + i;
  float draw = (float)proj[pos * PROJP + INTER + CONVD + h] + dt_bias[h];
  float dv = draw > 20.f ? draw : log1pf(expf(draw));
  float Ah = -expf(A_log[h]);
  __shared__ float s[CS];
  s[i] = dv * Ah;
  __syncthreads();
  for (int off = 1; off < CS; off <<= 1) {
    float t = (i >= off) ? s[i - off] : 0.f;
    __syncthreads();
    s[i] += t;
    __syncthreads();
  }
  long base = (long)bx * CS;
  dtv[base + i]  = dv;
  acum[base + i] = s[i];
  if (i == 0) cdec[bx] = expf(s[CS - 1]);
}

// ---------------------------------------------------------------- G[i][j] = C_i . B_j via MFMA (G=1, head-independent)
__global__ __launch_bounds__(256) void gmat_k(
    const bf16* __restrict__ Cmb, const bf16* __restrict__ Bmb, float* __restrict__ Gnt)
{
  int q  = blockIdx.x;              // quadrant: ti=q>>1, tj=q&1 (128x128 each)
  int bc = blockIdx.y;              // b*NC + ci
  long bl0 = (long)(bc >> 3) * LQ + (bc & 7) * CS;
  int wave = threadIdx.x >> 6, lane = threadIdx.x & 63;
  int quad = lane >> 4, r16 = lane & 15;
  int i0 = (q >> 1) * 128 + (wave >> 1) * 64;
  int j0 = (q & 1)  * 128 + (wave & 1)  * 64;

  f32x4 acc[4][4] = {};
  #pragma unroll
  for (int kt = 0; kt < 4; ++kt) {
    int k0 = kt * 32 + quad * 8;
    bf16x8 af[4], bfv[4];
    #pragma unroll
    for (int it = 0; it < 4; ++it)
      af[it] = *(const bf16x8*)&Cmb[(bl0 + i0 + it * 16 + r16) * NS + k0];
    #pragma unroll
    for (int nt = 0; nt < 4; ++nt)
      bfv[nt] = *(const bf16x8*)&Bmb[(bl0 + j0 + nt * 16 + r16) * NS + k0];
    #pragma unroll
    for (int it = 0; it < 4; ++it)
      #pragma unroll
      for (int nt = 0; nt < 4; ++nt)
        acc[it][nt] = __builtin_amdgcn_mfma_f32_16x16x32_bf16(af[it], bfv[nt], acc[it][nt], 0, 0, 0);
  }
  #pragma unroll
  for (int it = 0; it < 4; ++it)
    #pragma unroll
    for (int nt = 0; nt < 4; ++nt)
      #pragma unroll
      for (int reg = 0; reg < 4; ++reg) {
        int i = i0 + it * 16 + quad * 4 + reg;
        int j = j0 + nt * 16 + r16;
        Gnt[((long)bc * CS + i) * CS + j] = acc[it][nt][reg];
      }
}

// ---------------------------------------------------------------- chunk states via MFMA: state[p][n] = sum_j (X[j][p]*w_j)*B[j][n]
__global__ __launch_bounds__(256) void states_k(
    const bf16* __restrict__ xconv, const bf16* __restrict__ Bt,
    const float* __restrict__ dtv, const float* __restrict__ acum,
    bf16* __restrict__ st)
{
  int bx = blockIdx.x;          // bc*NH + h
  int h = bx & 63, bc = bx >> 6;
  int b = bc >> 3, ci = bc & 7;
  long bl0 = (long)b * LQ + ci * CS;
  long abase = ((long)(b * NH + h) * NC + ci) * CS;
  int t = threadIdx.x;
  int wave = t >> 6, lane = t & 63, quad = lane >> 4, r16 = lane & 15;

  __shared__ bf16 Xt[64][264];
  __shared__ float ws[CS];
  __shared__ float ac_s[CS];
  ac_s[t] = acum[abase + t];
  __syncthreads();
  float alast = ac_s[CS - 1];
  ws[t] = expf(alast - ac_s[t]) * dtv[abase + t];
  // stage X^T (coalesced: lanes span p)
  {
    int col = t & 63, grp = t >> 6;
    for (int r = 0; r < 64; ++r) {
      int j = grp * 64 + r;
      Xt[col][j] = xconv[(bl0 + j) * INTER + h * HD + col];
    }
  }
  __syncthreads();

  const bf16* btb = &Bt[(long)bc * NS * CS];
  f32x4 acc[8] = {};
  int p = wave * 16 + r16;
  #pragma unroll
  for (int kt = 0; kt < 8; ++kt) {
    int k0 = kt * 32 + quad * 8;
    bf16x8 xv = *(const bf16x8*)&Xt[p][k0];
    float w8[8];
    *(float4*)&w8[0] = *(const float4*)&ws[k0];
    *(float4*)&w8[4] = *(const float4*)&ws[k0 + 4];
    bf16x8 af;
    #pragma unroll
    for (int jj = 0; jj < 8; ++jj) af[jj] = (bf16)((float)xv[jj] * w8[jj]);
    #pragma unroll
    for (int nt = 0; nt < 8; ++nt) {
      bf16x8 bfv = *(const bf16x8*)&btb[(nt * 16 + r16) * CS + k0];
      acc[nt] = __builtin_amdgcn_mfma_f32_16x16x32_bf16(af, bfv, acc[nt], 0, 0, 0);
    }
  }
  #pragma unroll
  for (int nt = 0; nt < 8; ++nt)
    #pragma unroll
    for (int reg = 0; reg < 4; ++reg) {
      int prow = wave * 16 + quad * 4 + reg;
      int n = nt * 16 + r16;
      st[((long)bx * HD + prow) * NS + n] = (bf16)acc[nt][reg];
    }
}

// ---------------------------------------------------------------- inter-chunk scan, IN PLACE (st -> prev)
__global__ void scan_k(bf16* __restrict__ st, const float* __restrict__ cdec)
{
  long t = (long)blockIdx.x * 256 + threadIdx.x;  // (b,h,p,n)
  int n = (int)(t & 127);
  int p = (int)((t >> 7) & 63);
  int h = (int)((t >> 13) & 63);
  int b = (int)(t >> 19);
  float carry = 0.f;
  for (int ci = 0; ci < NC; ++ci) {
    long idx = (((long)(b * NC + ci) * NH + h) * HD + p) * NS + n;
    float v = (float)st[idx];
    st[idx] = (bf16)carry;
    carry = cdec[(b * NH + h) * NC + ci] * carry + v;
  }
}

// ---------------------------------------------------------------- fused Ydiag+Yoff+D*x via MFMA  (Y aliases xconv)
#define XTP 392   /* padded row length (bf16) for Xt: 384+8, keeps 16B alignment */
__global__ __launch_bounds__(256) void ymix_k(
    const bf16* __restrict__ xconv, const float* __restrict__ Gnt,
    const bf16* __restrict__ prev, const bf16* __restrict__ Cmb,
    const float* __restrict__ dtv, const float* __restrict__ acum,
    const float* __restrict__ Dp, bf16* __restrict__ Y)
{
  int bx = blockIdx.x;          // bc*NH + h
  int h = bx & 63, bc = bx >> 6;
  int b = bc >> 3, ci = bc & 7;
  long bl0 = (long)b * LQ + ci * CS;
  long abase = ((long)(b * NH + h) * NC + ci) * CS;
  int t = threadIdx.x;
  int wave = t >> 6, lane = t & 63;
  int quad = lane >> 4, r16 = lane & 15;
  int iw = wave * 64;

  __shared__ bf16 Xt[64][XTP];          // [p][k]: k<256 = X^T, k>=256 = prev^T
  __shared__ float a2s[CS], dts[CS], eas[CS];

  {
    float ac = acum[abase + t];
    a2s[t] = ac * LOG2E;
    dts[t] = dtv[abase + t];
    eas[t] = expf(ac);
  }
  {
    int col = t & 63, grp = t >> 6;
    for (int r = 0; r < 64; ++r) {
      int j = grp * 64 + r;
      Xt[col][j] = xconv[(bl0 + j) * INTER + h * HD + col];
    }
  }
  for (int r = 0; r < 32; ++r) {
    int idx = t + r * 256;
    int n = idx & 127, p = idx >> 7;
    Xt[p][256 + n] = prev[((long)bx * HD + p) * NS + n];
  }
  __syncthreads();

  f32x4 acc[4][4] = {};

  for (int kt = 0; kt < 12; ++kt) {
    int k0 = kt * 32;
    bool cpart = (k0 >= 256);
    if (!cpart && k0 > iw + 63) continue;   // whole k-tile above diagonal for this wave

    bf16x8 bfrag[4];
    #pragma unroll
    for (int nt = 0; nt < 4; ++nt)
      bfrag[nt] = *(const bf16x8*)&Xt[nt * 16 + r16][k0 + quad * 8];

    if (!cpart) {
      int j0 = k0 + quad * 8;
      float dt8[8], a28[8];
      *(float4*)&dt8[0] = *(const float4*)&dts[j0];
      *(float4*)&dt8[4] = *(const float4*)&dts[j0 + 4];
      *(float4*)&a28[0] = *(const float4*)&a2s[j0];
      *(float4*)&a28[4] = *(const float4*)&a2s[j0 + 4];
      #pragma unroll
      for (int it = 0; it < 4; ++it) {
        if (k0 > iw + it * 16 + 15) continue;   // zero tile
        int i = iw + it * 16 + r16;
        float a2i = a2s[i];
        const float* gp = &Gnt[((long)bc * CS + i) * CS + j0];
        float g[8];
        *(float4*)&g[0] = *(const float4*)gp;
        *(float4*)&g[4] = *(const float4*)(gp + 4);
        bf16x8 af;
        #pragma unroll
        for (int jj = 0; jj < 8; ++jj) {
          float v = g[jj] * dt8[jj] * exp2f(a2i - a28[jj]);
          v = (j0 + jj <= i) ? v : 0.f;
          af[jj] = (bf16)v;
        }
        #pragma unroll
        for (int nt = 0; nt < 4; ++nt)
          acc[it][nt] = __builtin_amdgcn_mfma_f32_16x16x32_bf16(af, bfrag[nt], acc[it][nt], 0, 0, 0);
      }
    } else {
      int n0 = k0 - 256 + quad * 8;
      #pragma unroll
      for (int it = 0; it < 4; ++it) {
        int i = iw + it * 16 + r16;
        float e = eas[i];
        bf16x8 cv = *(const bf16x8*)&Cmb[(bl0 + i) * NS + n0];
        bf16x8 af;
        #pragma unroll
        for (int jj = 0; jj < 8; ++jj)
          af[jj] = (bf16)(e * (float)cv[jj]);
        #pragma unroll
        for (int nt = 0; nt < 4; ++nt)
          acc[it][nt] = __builtin_amdgcn_mfma_f32_16x16x32_bf16(af, bfrag[nt], acc[it][nt], 0, 0, 0);
      }
    }
  }

  float Dh = Dp[h];
  #pragma unroll
  for (int it = 0; it < 4; ++it)
    #pragma unroll
    for (int nt = 0; nt < 4; ++nt) {
      int i0 = iw + it * 16 + quad * 4;
      int p  = nt * 16 + r16;
      bf16x4 xv = *(const bf16x4*)&Xt[p][i0];
      #pragma unroll
      for (int reg = 0; reg < 4; ++reg) {
        float v = acc[it][nt][reg] + Dh * (float)xv[reg];
        Y[(bl0 + i0 + reg) * INTER + h * HD + p] = (bf16)v;
      }
    }
}

// ---------------------------------------------------------------- gate*silu + RMS norm, IN PLACE
__global__ __launch_bounds__(256) void norm_k(
    bf16* __restrict__ Y, const bf16* __restrict__ proj,
    const float* __restrict__ norm_w)
{
  long bl = blockIdx.x;
  int t = threadIdx.x;
  __shared__ float yb[INTER];
  __shared__ float red[256];
  float ss = 0.f;
  for (int r = 0; r < 16; ++r) {
    int ch = t + r * 256;
    float g = (float)proj[bl * PROJP + ch];
    float yv = (float)Y[bl * INTER + ch] * siluf(g);
    yb[ch] = yv;
    ss += yv * yv;
  }
  red[t] = ss;
  __syncthreads();
  for (int s = 128; s > 0; s >>= 1) {
    if (t < s) red[t] += red[t + s];
    __syncthreads();
  }
  float scale = rsqrtf(red[0] / (float)INTER + EPSF);
  for (int r = 0; r < 16; ++r) {
    int ch = t + r * 256;
    Y[bl * INTER + ch] = (bf16)(yb[ch] * scale * norm_w[ch]);
  }
}

// ---------------------------------------------------------------- launch
extern "C" void kernel_launch(void* const* d_in, const int* in_sizes, int n_in,
                              void* d_out, int out_size, void* d_ws, size_t ws_size,
                              hipStream_t stream)
{
  (void)in_sizes; (void)n_in; (void)out_size; (void)ws_size;
  const float* hidden  = (const float*)d_in[0];
  const float* W_in    = (const float*)d_in[1];
  const float* conv_w  = (const float*)d_in[2];
  const float* conv_b  = (const float*)d_in[3];
  const float* dt_bias = (const float*)d_in[4];
  const float* A_log   = (const float*)d_in[5];
  const float* Dp      = (const float*)d_in[6];
  const float* norm_w  = (const float*)d_in[7];
  const float* W_out   = (const float*)d_in[8];
  float* out = (float*)d_out;

  // ---- workspace layout with lifetime-based aliasing (peak ~124.7 MiB)
  char* ws    = (char*)d_ws;
  bf16* projb = (bf16*)(ws);                         // 70,254,592  [gemm1 .. norm]
  char* base2 = ws + 70254592;
  bf16*  hb    = (bf16*)(base2);                     // 16,777,216  [stage1 only]
  bf16*  winb  = (bf16*)(base2 + 16777216);          // 35,127,296  [stage1 only]
  bf16*  xconv = (bf16*)(base2);                     // 33,554,432  [conv .. ymix] = Y
  bf16*  st    = (bf16*)(base2 + 33554432);          // 16,777,216  [states .. ymix]
  float* Gnt   = (float*)(base2 + 50331648);         //  4,194,304
  bf16*  Bmb   = (bf16*)(base2 + 54525952);          //  1,048,576
  bf16*  Cmb   = (bf16*)(base2 + 55574528);          //  1,048,576
  float* dtv   = (float*)(base2 + 56623104);         //  1,048,576
  float* acum  = (float*)(base2 + 57671680);         //  1,048,576
  float* cdec  = (float*)(base2 + 58720256);         //      4,096
  bf16*  Bt    = (bf16*)(base2 + 58724352);          //  1,048,576 (B transposed per chunk)
  bf16*  Yb    = xconv;                              // alias (disjoint per-block tiles)
  bf16*  woutb = st;                                 // alias st (dead after ymix), exact 16 MiB

  // stage 1: casts + in-projection GEMM
  cast4_k<<<dim3((unsigned)((MTOT * (long)DMODEL / 4 + 255) / 256)), 256, 0, stream>>>(
      hidden, hb, (long)MTOT * DMODEL / 4);
  cast_pad_win_k<<<dim3((unsigned)(((long)PROJP * (DMODEL / 4) + 255) / 256)), 256, 0, stream>>>(
      W_in, winb);
  gemm_bt<<<dim3(PROJP / BN, MTOT / BM), 256, 0, stream>>>(
      hb, winb, projb, nullptr, MTOT, PROJP, DMODEL, 0);

  // stage 2: conv + SSD
  conv_silu_k<<<dim3(CONVD / 256, MTOT), 256, 0, stream>>>(
      projb, conv_w, conv_b, xconv, Bmb, Cmb, Bt);
  dt_prep_k<<<dim3(BQ * NH * NC), CS, 0, stream>>>(
      projb, dt_bias, A_log, dtv, acum, cdec);
  gmat_k<<<dim3(4, BQ * NC), 256, 0, stream>>>(Cmb, Bmb, Gnt);
  states_k<<<dim3(BQ * NC * NH), 256, 0, stream>>>(xconv, Bt, dtv, acum, st);
  scan_k<<<dim3(BQ * NH * HD * NS / 256), 256, 0, stream>>>(st, cdec);
  ymix_k<<<dim3(BQ * NC * NH), 256, 0, stream>>>(
      xconv, Gnt, st, Cmb, dtv, acum, Dp, Yb);

  // stage 3: norm + out-projection GEMM
  cast4_k<<<dim3((unsigned)((DMODEL * (long)INTER / 4 + 255) / 256)), 256, 0, stream>>>(
      W_out, woutb, (long)DMODEL * INTER / 4);
  norm_k<<<dim3(MTOT), 256, 0, stream>>>(Yb, projb, norm_w);
  gemm_bt<<<dim3(DMODEL / BN, MTOT / BM), 256, 0, stream>>>(
      Yb, woutb, nullptr, out, MTOT, DMODEL, INTER, 1);
}